// Round 8
// baseline (221.356 us; speedup 1.0000x reference)
//
#include <hip/hip_runtime.h>
#include <hip/hip_bf16.h>

// GCN 2-layer forward — bucketed CSR build + bf16 intermediates.
// R8: 4-deep memory-level parallelism in both gather kernels (32-edge steps
// in layer12, 64-edge steps in gather2); int4-vectorized bfine loops.

constexpr int N = 100000;
constexpr int E = 1000000;
constexpr int NB = (N + 511) / 512;   // 196 buckets of 512 dst nodes
constexpr int CAP = 6144;             // mean fill 5102, sd ~71 -> 14 sigma
constexpr int CSTRIDE = 32;           // cursor padding: 1 per 128B line
constexpr int CHUNK = 4096;           // edges per k_bfill block
constexpr int NBLK = (E + CHUNK - 1) / CHUNK;  // 245
constexpr int NPW = 13;               // nodes per wave (layer12/gather2)
constexpr int NW = (N + NPW - 1) / NPW;        // 7693 waves
constexpr int NWBLK = (NW + 3) / 4;            // 1924 blocks

__device__ __forceinline__ float rl_f(float v, int l) {
    return __int_as_float(__builtin_amdgcn_readlane(__float_as_int(v), l));
}
__device__ __forceinline__ float bflo(unsigned u) { return __uint_as_float(u << 16); }
__device__ __forceinline__ float bfhi(unsigned u) { return __uint_as_float(u & 0xffff0000u); }

// Two-pass LDS-binned scatter into coarse buckets.
// pack = (dst&511)<<17 | src  (src < 2^17).
__global__ void k_bfill(const int* __restrict__ src, const int* __restrict__ dst,
                        int* __restrict__ cursor, int* __restrict__ bkt) {
    __shared__ int hist[256];
    __shared__ int lbase[256];
    __shared__ int gbase[256];
    __shared__ int lcur[256];
    __shared__ int stage[CHUNK];
    __shared__ unsigned char sbkt[CHUNK];
    int t = threadIdx.x;
    int e0 = blockIdx.x * CHUNK;
    int cnt = min(CHUNK, E - e0);

    hist[t] = 0;
    __syncthreads();
    for (int j = t; j < cnt; j += 256)
        atomicAdd(&hist[dst[e0 + j] >> 9], 1);
    __syncthreads();
    int h = hist[t];
    lbase[t] = h;
    __syncthreads();
    for (int off = 1; off < 256; off <<= 1) {   // Hillis-Steele inclusive
        int x = (t >= off) ? lbase[t - off] : 0;
        __syncthreads();
        lbase[t] += x;
        __syncthreads();
    }
    int excl = lbase[t] - h;
    __syncthreads();
    lbase[t] = excl;
    lcur[t] = 0;
    if (t < NB) gbase[t] = h ? atomicAdd(&cursor[t * CSTRIDE], h) : 0;
    __syncthreads();
    for (int j = t; j < cnt; j += 256) {        // stage bucket-sorted
        int d = dst[e0 + j];
        int b = d >> 9;
        int pos = lbase[b] + atomicAdd(&lcur[b], 1);
        stage[pos] = ((d & 511) << 17) | src[e0 + j];
        sbkt[pos] = (unsigned char)b;
    }
    __syncthreads();
    for (int j = t; j < cnt; j += 256) {        // contiguous-run copy out
        int b = sbkt[j];
        int gpos = gbase[b] + (j - lbase[b]);
        if (gpos < CAP) bkt[b * CAP + gpos] = stage[j];
    }
}

// One workgroup per bucket: scan all bucket counts for global base, LDS
// histogram of 512 local nodes, LDS scan, write row_ptr/dinv, place csr_src.
__global__ void k_bfine(const int* __restrict__ cursor, const int* __restrict__ bkt,
                        int* __restrict__ row_ptr, float* __restrict__ dinv,
                        int* __restrict__ csr_src) {
    __shared__ int sd[256];
    __shared__ int cnt[512];
    __shared__ int excl[512];
    __shared__ int s2[256];
    int b = blockIdx.x;
    int t = threadIdx.x;
    int c = (t < NB) ? cursor[t * CSTRIDE] : 0;
    sd[t] = c;
    __syncthreads();
    for (int off = 1; off < 256; off <<= 1) {
        int x = (t >= off) ? sd[t - off] : 0;
        __syncthreads();
        sd[t] += x;
        __syncthreads();
    }
    int m = cursor[b * CSTRIDE];
    int base = sd[b] - m;                       // exclusive prefix of bucket b
    if (b == 0 && t == 0) row_ptr[N] = E;
    const int* bb = bkt + b * CAP;
    const int4* bb4 = (const int4*)bb;          // CAP%4==0 -> aligned
    int m4 = m >> 2;
    cnt[t] = 0; cnt[t + 256] = 0;
    __syncthreads();
    for (int j = t; j < m4; j += 256) {
        int4 v = bb4[j];
        atomicAdd(&cnt[v.x >> 17], 1); atomicAdd(&cnt[v.y >> 17], 1);
        atomicAdd(&cnt[v.z >> 17], 1); atomicAdd(&cnt[v.w >> 17], 1);
    }
    for (int j = (m4 << 2) + t; j < m; j += 256) atomicAdd(&cnt[bb[j] >> 17], 1);
    __syncthreads();
    int pairSum = cnt[2 * t] + cnt[2 * t + 1];
    s2[t] = pairSum;
    __syncthreads();
    for (int off = 1; off < 256; off <<= 1) {
        int x = (t >= off) ? s2[t - off] : 0;
        __syncthreads();
        s2[t] += x;
        __syncthreads();
    }
    int exclPair = s2[t] - pairSum;
    excl[2 * t] = exclPair;
    excl[2 * t + 1] = exclPair + cnt[2 * t];
    __syncthreads();
#pragma unroll
    for (int hh = 0; hh < 2; ++hh) {
        int k = t + hh * 256;
        int node = b * 512 + k;
        if (node < N) {
            row_ptr[node] = base + excl[k];
            dinv[node] = rsqrtf((float)(cnt[k] + 1));
        }
    }
    __syncthreads();
    for (int j = t; j < m4; j += 256) {
        int4 v = bb4[j];
        int p0 = atomicAdd(&excl[v.x >> 17], 1); csr_src[base + p0] = v.x & 0x1FFFF;
        int p1 = atomicAdd(&excl[v.y >> 17], 1); csr_src[base + p1] = v.y & 0x1FFFF;
        int p2 = atomicAdd(&excl[v.z >> 17], 1); csr_src[base + p2] = v.z & 0x1FFFF;
        int p3 = atomicAdd(&excl[v.w >> 17], 1); csr_src[base + p3] = v.w & 0x1FFFF;
    }
    for (int j = (m4 << 2) + t; j < m; j += 256) {
        int v = bb[j];
        int p = atomicAdd(&excl[v >> 17], 1);
        csr_src[base + p] = v & 0x1FFFF;
    }
}

// h1s[row][c] = (X[row] . W1[:,c]) * dinv[row], stored bf16 (packed stores).
// Also zeroes dummy rows h1s[N] / h2s[N] (gather padding targets).
__global__ void k_gemm1(const float* __restrict__ X, const float* __restrict__ W1,
                        const float* __restrict__ dinv, __hip_bfloat16* __restrict__ h1s,
                        __hip_bfloat16* __restrict__ h2s) {
    int t = threadIdx.x;
    int lane = t & 63;
    int wid = (blockIdx.x * 256 + t) >> 6;  // 4096 waves
    if (blockIdx.x == 0) {
        if (t < 64) h1s[(size_t)N * 64 + t] = __float2bfloat16(0.f);
        if (t < 16) h2s[(size_t)N * 16 + t] = __float2bfloat16(0.f);
    }
    float w1[64];
#pragma unroll
    for (int k = 0; k < 64; ++k) w1[k] = W1[k * 64 + lane];
    for (int row = wid; row < N; row += 4096) {
        float x = X[(size_t)row * 64 + lane];
        float acc = 0.f;
#pragma unroll
        for (int k = 0; k < 64; ++k) acc = fmaf(rl_f(x, k), w1[k], acc);
        acc *= dinv[row];
        float up = __shfl_xor(acc, 1);
        if (!(lane & 1)) {
            __hip_bfloat162 p;
            p.x = __float2bfloat16(acc);
            p.y = __float2bfloat16(up);
            *(__hip_bfloat162*)(h1s + (size_t)row * 64 + lane) = p;
        }
    }
}

// Fused: gather layer-1 (CSR), +b1, relu, y1@W2, scale -> h2s (bf16).
// Wave handles NPW contiguous nodes. 32 edges per step = 4 independent uint4
// gathers per lane in flight (slots j*32 + {0,8,16,24} + g8); dummy zero row
// N pads — no predication, no divergence.
__global__ void k_layer12(const int* __restrict__ row_ptr, const int* __restrict__ csr_src,
                          const float* __restrict__ dinv, const __hip_bfloat16* __restrict__ h1s,
                          const float* __restrict__ b1, const float* __restrict__ W2,
                          __hip_bfloat16* __restrict__ h2s) {
    __shared__ float sy[4][8][72];
    int t = threadIdx.x;
    int lane = t & 63;
    int w = t >> 6;
    int g8 = lane >> 3;                         // edge sub-slot
    int qo = (lane & 7) << 4;                   // byte offset of 16B feat slice
    int g16 = lane >> 4, c16 = lane & 15;       // W2-stage layout
    int wid = blockIdx.x * 4 + w;
    int d0 = wid * NPW;
    if (d0 >= N) return;
    int dend = min(d0 + NPW, N);
    float w2[16];
#pragma unroll
    for (int j = 0; j < 16; ++j) w2[j] = W2[(g16 * 16 + j) * 16 + c16];
    float b1v = b1[lane];
    const char* Hb = (const char*)h1s;

    int rp0 = row_ptr[d0];
    for (int d = d0; d < dend; ++d) {
        int rp1 = row_ptr[d + 1];
        float dv = dinv[d];
        float a[8] = {0, 0, 0, 0, 0, 0, 0, 0};
        float a2b[8] = {0, 0, 0, 0, 0, 0, 0, 0};
        if (g8 == 0) {                          // self term (one 8-lane load)
            uint4 u = *(const uint4*)(Hb + (((unsigned)d << 7) | qo));
            a[0] = bflo(u.x); a[1] = bfhi(u.x); a[2] = bflo(u.y); a[3] = bfhi(u.y);
            a[4] = bflo(u.z); a[5] = bfhi(u.z); a[6] = bflo(u.w); a[7] = bfhi(u.w);
        }
        for (int base = rp0; base < rp1; base += 64) {   // wave-uniform bounds
            int nloc = min(64, rp1 - base);
            int sidx = (lane < nloc) ? csr_src[base + lane] : N;   // pad -> zero row
            int steps = (nloc + 31) >> 5;       // 32 edges per iteration
            for (int j = 0; j < steps; ++j) {
                int b0 = (j << 5) | g8;
                int s0 = __shfl(sidx, b0);
                int s1 = __shfl(sidx, b0 | 8);
                int s2v = __shfl(sidx, b0 | 16);
                int s3v = __shfl(sidx, b0 | 24);
                uint4 u0 = *(const uint4*)(Hb + (((unsigned)s0 << 7) | qo));
                uint4 u1 = *(const uint4*)(Hb + (((unsigned)s1 << 7) | qo));
                uint4 u2 = *(const uint4*)(Hb + (((unsigned)s2v << 7) | qo));
                uint4 u3 = *(const uint4*)(Hb + (((unsigned)s3v << 7) | qo));
                a[0] += bflo(u0.x); a[1] += bfhi(u0.x); a[2] += bflo(u0.y); a[3] += bfhi(u0.y);
                a[4] += bflo(u0.z); a[5] += bfhi(u0.z); a[6] += bflo(u0.w); a[7] += bfhi(u0.w);
                a2b[0] += bflo(u1.x); a2b[1] += bfhi(u1.x); a2b[2] += bflo(u1.y); a2b[3] += bfhi(u1.y);
                a2b[4] += bflo(u1.z); a2b[5] += bfhi(u1.z); a2b[6] += bflo(u1.w); a2b[7] += bfhi(u1.w);
                a[0] += bflo(u2.x); a[1] += bfhi(u2.x); a[2] += bflo(u2.y); a[3] += bfhi(u2.y);
                a[4] += bflo(u2.z); a[5] += bfhi(u2.z); a[6] += bflo(u2.w); a[7] += bfhi(u2.w);
                a2b[0] += bflo(u3.x); a2b[1] += bfhi(u3.x); a2b[2] += bflo(u3.y); a2b[3] += bfhi(u3.y);
                a2b[4] += bflo(u3.z); a2b[5] += bfhi(u3.z); a2b[6] += bflo(u3.w); a2b[7] += bfhi(u3.w);
            }
        }
        rp0 = rp1;
        // LDS transpose: partials (8 groups x 64 feats) -> y[feat=lane]
        float* row = &sy[w][g8][(lane & 7) << 3];
        *(float4*)row = make_float4(a[0] + a2b[0], a[1] + a2b[1], a[2] + a2b[2], a[3] + a2b[3]);
        *(float4*)(row + 4) = make_float4(a[4] + a2b[4], a[5] + a2b[5], a[6] + a2b[6], a[7] + a2b[7]);
        __builtin_amdgcn_s_waitcnt(0);          // lgkmcnt(0): within-wave LDS order
        float ysum = sy[w][0][lane] + sy[w][1][lane] + sy[w][2][lane] + sy[w][3][lane]
                   + sy[w][4][lane] + sy[w][5][lane] + sy[w][6][lane] + sy[w][7][lane];
        float y = fmaxf(fmaf(dv, ysum, b1v), 0.f);
        // h2[c] = sum_k y[k]*W2[k][c]; group g16 covers k = g16*16..+15
        float o = 0.f;
#pragma unroll
        for (int j = 0; j < 16; ++j) o = fmaf(__shfl(y, (lane & 48) | j), w2[j], o);
        o += __shfl_xor(o, 16);
        o += __shfl_xor(o, 32);
        o *= dv;
        float oup = __shfl_xor(o, 1);
        if (lane < 16 && !(lane & 1)) {
            __hip_bfloat162 p;
            p.x = __float2bfloat16(o);
            p.y = __float2bfloat16(oup);
            *(__hip_bfloat162*)(h2s + (size_t)d * 16 + lane) = p;
        }
    }
}

// out[d] = dinv[d]*(h2s[d] + sum_in h2s[s]) + b2.  64 edges per step = 4
// independent uint2 gathers per lane in flight; dummy-row padding; float4 out.
__global__ void k_gather2(const int* __restrict__ row_ptr, const int* __restrict__ csr_src,
                          const float* __restrict__ dinv, const __hip_bfloat16* __restrict__ h2s,
                          const float* __restrict__ b2, float* __restrict__ out) {
    int t = threadIdx.x;
    int lane = t & 63;
    int g4 = lane >> 2;                         // edge sub-slot (16)
    int q2 = lane & 3;                          // 8B feat slice
    int qo = q2 << 3;
    int wid = blockIdx.x * 4 + (t >> 6);
    int d0 = wid * NPW;
    if (d0 >= N) return;
    int dend = min(d0 + NPW, N);
    float b2v[4];
#pragma unroll
    for (int k = 0; k < 4; ++k) b2v[k] = b2[q2 * 4 + k];
    const char* Hb = (const char*)h2s;

    int rp0 = row_ptr[d0];
    for (int d = d0; d < dend; ++d) {
        int rp1 = row_ptr[d + 1];
        float dv = dinv[d];
        float a[4] = {0, 0, 0, 0};
        float ab[4] = {0, 0, 0, 0};
        if (g4 == 0) {                          // self term
            uint2 u = *(const uint2*)(Hb + (((unsigned)d << 5) | qo));
            a[0] = bflo(u.x); a[1] = bfhi(u.x); a[2] = bflo(u.y); a[3] = bfhi(u.y);
        }
        for (int base = rp0; base < rp1; base += 64) {
            int nloc = min(64, rp1 - base);
            int sidx = (lane < nloc) ? csr_src[base + lane] : N;
            int steps = (nloc + 63) >> 6;       // 64 edges per iteration
            for (int j = 0; j < steps; ++j) {
                int b0 = (j << 6) | g4;
                int s0 = __shfl(sidx, b0);
                int s1 = __shfl(sidx, b0 | 16);
                int s2v = __shfl(sidx, b0 | 32);
                int s3v = __shfl(sidx, b0 | 48);
                uint2 u0 = *(const uint2*)(Hb + (((unsigned)s0 << 5) | qo));
                uint2 u1 = *(const uint2*)(Hb + (((unsigned)s1 << 5) | qo));
                uint2 u2 = *(const uint2*)(Hb + (((unsigned)s2v << 5) | qo));
                uint2 u3 = *(const uint2*)(Hb + (((unsigned)s3v << 5) | qo));
                a[0] += bflo(u0.x); a[1] += bfhi(u0.x); a[2] += bflo(u0.y); a[3] += bfhi(u0.y);
                ab[0] += bflo(u1.x); ab[1] += bfhi(u1.x); ab[2] += bflo(u1.y); ab[3] += bfhi(u1.y);
                a[0] += bflo(u2.x); a[1] += bfhi(u2.x); a[2] += bflo(u2.y); a[3] += bfhi(u2.y);
                ab[0] += bflo(u3.x); ab[1] += bfhi(u3.x); ab[2] += bflo(u3.y); ab[3] += bfhi(u3.y);
            }
        }
        rp0 = rp1;
#pragma unroll
        for (int k = 0; k < 4; ++k) {
            a[k] += ab[k];
            a[k] += __shfl_xor(a[k], 4);
            a[k] += __shfl_xor(a[k], 8);
            a[k] += __shfl_xor(a[k], 16);
            a[k] += __shfl_xor(a[k], 32);
        }
        if (lane < 4) {
            float4 r;
            r.x = fmaf(dv, a[0], b2v[0]);
            r.y = fmaf(dv, a[1], b2v[1]);
            r.z = fmaf(dv, a[2], b2v[2]);
            r.w = fmaf(dv, a[3], b2v[3]);
            *(float4*)(out + (size_t)d * 16 + q2 * 4) = r;
        }
    }
}

extern "C" void kernel_launch(void* const* d_in, const int* in_sizes, int n_in,
                              void* d_out, int out_size, void* d_ws, size_t ws_size,
                              hipStream_t stream) {
    const float* X  = (const float*)d_in[0];
    const int*   ei = (const int*)d_in[1];  // [2, E] int32: src then dst
    const float* W1 = (const float*)d_in[2];
    const float* b1 = (const float*)d_in[3];
    const float* W2 = (const float*)d_in[4];
    const float* b2 = (const float*)d_in[5];
    float* out = (float*)d_out;

    int* cursor  = (int*)d_ws;                     // NB*CSTRIDE = 6272
    int* row_ptr = cursor + NB * CSTRIDE;          // N+4 (pad keeps h1s 16B-aligned)
    int* bkt     = row_ptr + N + 4;                // NB*CAP
    int* csr_src = bkt + NB * CAP;                 // E
    float* dinv  = (float*)(csr_src + E);          // N
    __hip_bfloat16* h1s = (__hip_bfloat16*)(dinv + N);  // (N+1)*64, 16B-aligned
    __hip_bfloat16* h2s = h1s + (size_t)(N + 1) * 64;   // (N+1)*16, 16B-aligned

    const int* src = ei;
    const int* dst = ei + E;

    hipMemsetAsync(cursor, 0, NB * CSTRIDE * sizeof(int), stream);
    k_bfill<<<NBLK, 256, 0, stream>>>(src, dst, cursor, bkt);
    k_bfine<<<NB, 256, 0, stream>>>(cursor, bkt, row_ptr, dinv, csr_src);
    k_gemm1<<<1024, 256, 0, stream>>>(X, W1, dinv, h1s, h2s);
    k_layer12<<<NWBLK, 256, 0, stream>>>(row_ptr, csr_src, dinv, h1s, b1, W2, h2s);
    k_gather2<<<NWBLK, 256, 0, stream>>>(row_ptr, csr_src, dinv, h2s, b2, out);
}

// Round 9
// 193.987 us; speedup vs baseline: 1.1411x; 1.1411x over previous
//
#include <hip/hip_runtime.h>
#include <hip/hip_bf16.h>

// GCN 2-layer forward — bucketed CSR build + bf16 intermediates.
// R9: layer12/gather2 back to R7 2-deep inner loops (32 VGPR), NPW 13->6
// (TLP over per-wave MLP: R8 showed 4-deep MLP cost occupancy 54->38% and
// regressed); gemm1 uses LDS-broadcast X so k-broadcast rides the LDS pipe.

constexpr int N = 100000;
constexpr int E = 1000000;
constexpr int NB = (N + 511) / 512;   // 196 buckets of 512 dst nodes
constexpr int CAP = 6144;             // mean fill 5102, sd ~71 -> 14 sigma
constexpr int CSTRIDE = 32;           // cursor padding: 1 per 128B line
constexpr int CHUNK = 4096;           // edges per k_bfill block
constexpr int NBLK = (E + CHUNK - 1) / CHUNK;  // 245
constexpr int NPW = 6;                // nodes per wave (layer12/gather2)
constexpr int NW = (N + NPW - 1) / NPW;        // 16667 waves
constexpr int NWBLK = (NW + 3) / 4;            // 4167 blocks

__device__ __forceinline__ float bflo(unsigned u) { return __uint_as_float(u << 16); }
__device__ __forceinline__ float bfhi(unsigned u) { return __uint_as_float(u & 0xffff0000u); }

// Two-pass LDS-binned scatter into coarse buckets.
// pack = (dst&511)<<17 | src  (src < 2^17).
__global__ void k_bfill(const int* __restrict__ src, const int* __restrict__ dst,
                        int* __restrict__ cursor, int* __restrict__ bkt) {
    __shared__ int hist[256];
    __shared__ int lbase[256];
    __shared__ int gbase[256];
    __shared__ int lcur[256];
    __shared__ int stage[CHUNK];
    __shared__ unsigned char sbkt[CHUNK];
    int t = threadIdx.x;
    int e0 = blockIdx.x * CHUNK;
    int cnt = min(CHUNK, E - e0);

    hist[t] = 0;
    __syncthreads();
    for (int j = t; j < cnt; j += 256)
        atomicAdd(&hist[dst[e0 + j] >> 9], 1);
    __syncthreads();
    int h = hist[t];
    lbase[t] = h;
    __syncthreads();
    for (int off = 1; off < 256; off <<= 1) {   // Hillis-Steele inclusive
        int x = (t >= off) ? lbase[t - off] : 0;
        __syncthreads();
        lbase[t] += x;
        __syncthreads();
    }
    int excl = lbase[t] - h;
    __syncthreads();
    lbase[t] = excl;
    lcur[t] = 0;
    if (t < NB) gbase[t] = h ? atomicAdd(&cursor[t * CSTRIDE], h) : 0;
    __syncthreads();
    for (int j = t; j < cnt; j += 256) {        // stage bucket-sorted
        int d = dst[e0 + j];
        int b = d >> 9;
        int pos = lbase[b] + atomicAdd(&lcur[b], 1);
        stage[pos] = ((d & 511) << 17) | src[e0 + j];
        sbkt[pos] = (unsigned char)b;
    }
    __syncthreads();
    for (int j = t; j < cnt; j += 256) {        // contiguous-run copy out
        int b = sbkt[j];
        int gpos = gbase[b] + (j - lbase[b]);
        if (gpos < CAP) bkt[b * CAP + gpos] = stage[j];
    }
}

// One workgroup per bucket: scan all bucket counts for global base, LDS
// histogram of 512 local nodes, LDS scan, write row_ptr/dinv, place csr_src.
__global__ void k_bfine(const int* __restrict__ cursor, const int* __restrict__ bkt,
                        int* __restrict__ row_ptr, float* __restrict__ dinv,
                        int* __restrict__ csr_src) {
    __shared__ int sd[256];
    __shared__ int cnt[512];
    __shared__ int excl[512];
    __shared__ int s2[256];
    int b = blockIdx.x;
    int t = threadIdx.x;
    int c = (t < NB) ? cursor[t * CSTRIDE] : 0;
    sd[t] = c;
    __syncthreads();
    for (int off = 1; off < 256; off <<= 1) {
        int x = (t >= off) ? sd[t - off] : 0;
        __syncthreads();
        sd[t] += x;
        __syncthreads();
    }
    int m = cursor[b * CSTRIDE];
    int base = sd[b] - m;                       // exclusive prefix of bucket b
    if (b == 0 && t == 0) row_ptr[N] = E;
    const int* bb = bkt + b * CAP;
    const int4* bb4 = (const int4*)bb;          // CAP%4==0 -> aligned
    int m4 = m >> 2;
    cnt[t] = 0; cnt[t + 256] = 0;
    __syncthreads();
    for (int j = t; j < m4; j += 256) {
        int4 v = bb4[j];
        atomicAdd(&cnt[v.x >> 17], 1); atomicAdd(&cnt[v.y >> 17], 1);
        atomicAdd(&cnt[v.z >> 17], 1); atomicAdd(&cnt[v.w >> 17], 1);
    }
    for (int j = (m4 << 2) + t; j < m; j += 256) atomicAdd(&cnt[bb[j] >> 17], 1);
    __syncthreads();
    int pairSum = cnt[2 * t] + cnt[2 * t + 1];
    s2[t] = pairSum;
    __syncthreads();
    for (int off = 1; off < 256; off <<= 1) {
        int x = (t >= off) ? s2[t - off] : 0;
        __syncthreads();
        s2[t] += x;
        __syncthreads();
    }
    int exclPair = s2[t] - pairSum;
    excl[2 * t] = exclPair;
    excl[2 * t + 1] = exclPair + cnt[2 * t];
    __syncthreads();
#pragma unroll
    for (int hh = 0; hh < 2; ++hh) {
        int k = t + hh * 256;
        int node = b * 512 + k;
        if (node < N) {
            row_ptr[node] = base + excl[k];
            dinv[node] = rsqrtf((float)(cnt[k] + 1));
        }
    }
    __syncthreads();
    for (int j = t; j < m4; j += 256) {
        int4 v = bb4[j];
        int p0 = atomicAdd(&excl[v.x >> 17], 1); csr_src[base + p0] = v.x & 0x1FFFF;
        int p1 = atomicAdd(&excl[v.y >> 17], 1); csr_src[base + p1] = v.y & 0x1FFFF;
        int p2 = atomicAdd(&excl[v.z >> 17], 1); csr_src[base + p2] = v.z & 0x1FFFF;
        int p3 = atomicAdd(&excl[v.w >> 17], 1); csr_src[base + p3] = v.w & 0x1FFFF;
    }
    for (int j = (m4 << 2) + t; j < m; j += 256) {
        int v = bb[j];
        int p = atomicAdd(&excl[v >> 17], 1);
        csr_src[base + p] = v & 0x1FFFF;
    }
}

// h1s[row][c] = (X[row] . W1[:,c]) * dinv[row], stored bf16 (packed stores).
// X rows staged in LDS; k-broadcast via ds_read (LDS pipe) dual-issues with
// the FMA stream (VALU pipe) — replaces the serialized readlane chain.
// Also zeroes dummy rows h1s[N] / h2s[N] (gather padding targets).
__global__ void k_gemm1(const float* __restrict__ X, const float* __restrict__ W1,
                        const float* __restrict__ dinv, __hip_bfloat16* __restrict__ h1s,
                        __hip_bfloat16* __restrict__ h2s) {
    __shared__ float sX[4][4][64];              // [wave][row][feat]
    int t = threadIdx.x;
    int lane = t & 63;
    int w = t >> 6;
    int wid = (blockIdx.x * 256 + t) >> 6;      // 4096 waves
    if (blockIdx.x == 0) {
        if (t < 64) h1s[(size_t)N * 64 + t] = __float2bfloat16(0.f);
        if (t < 16) h2s[(size_t)N * 16 + t] = __float2bfloat16(0.f);
    }
    float w1[64];
#pragma unroll
    for (int k = 0; k < 64; ++k) w1[k] = W1[k * 64 + lane];
    for (int r4 = wid * 4; r4 < N; r4 += 4096 * 4) {
#pragma unroll
        for (int j = 0; j < 4; ++j) sX[w][j][lane] = X[(size_t)(r4 + j) * 64 + lane];
        __builtin_amdgcn_s_waitcnt(0);          // own wave's LDS writes visible
#pragma unroll
        for (int j = 0; j < 4; ++j) {
            float acc = 0.f;
#pragma unroll
            for (int k = 0; k < 64; ++k) acc = fmaf(sX[w][j][k], w1[k], acc);
            acc *= dinv[r4 + j];
            float up = __shfl_xor(acc, 1);
            if (!(lane & 1)) {
                __hip_bfloat162 p;
                p.x = __float2bfloat16(acc);
                p.y = __float2bfloat16(up);
                *(__hip_bfloat162*)(h1s + (size_t)(r4 + j) * 64 + lane) = p;
            }
        }
    }
}

// Fused: gather layer-1 (CSR), +b1, relu, y1@W2, scale -> h2s (bf16).
// Wave handles NPW contiguous nodes. 8 edges per uint4 load, 2-deep unroll;
// dummy zero row N pads — no predication, no divergence.
__global__ void k_layer12(const int* __restrict__ row_ptr, const int* __restrict__ csr_src,
                          const float* __restrict__ dinv, const __hip_bfloat16* __restrict__ h1s,
                          const float* __restrict__ b1, const float* __restrict__ W2,
                          __hip_bfloat16* __restrict__ h2s) {
    __shared__ float sy[4][8][72];
    int t = threadIdx.x;
    int lane = t & 63;
    int w = t >> 6;
    int g8 = lane >> 3;                         // edge sub-slot
    int qo = (lane & 7) << 4;                   // byte offset of 16B feat slice
    int g16 = lane >> 4, c16 = lane & 15;       // W2-stage layout
    int wid = blockIdx.x * 4 + w;
    int d0 = wid * NPW;
    if (d0 >= N) return;
    int dend = min(d0 + NPW, N);
    float w2[16];
#pragma unroll
    for (int j = 0; j < 16; ++j) w2[j] = W2[(g16 * 16 + j) * 16 + c16];
    float b1v = b1[lane];
    const char* Hb = (const char*)h1s;

    int rp0 = row_ptr[d0];
    for (int d = d0; d < dend; ++d) {
        int rp1 = row_ptr[d + 1];
        float dv = dinv[d];
        float a[8] = {0, 0, 0, 0, 0, 0, 0, 0};
        if (g8 == 0) {                          // self term (one 8-lane load)
            uint4 u = *(const uint4*)(Hb + (((unsigned)d << 7) | qo));
            a[0] = bflo(u.x); a[1] = bfhi(u.x); a[2] = bflo(u.y); a[3] = bfhi(u.y);
            a[4] = bflo(u.z); a[5] = bfhi(u.z); a[6] = bflo(u.w); a[7] = bfhi(u.w);
        }
        for (int base = rp0; base < rp1; base += 64) {   // wave-uniform bounds
            int nloc = min(64, rp1 - base);
            int sidx = (lane < nloc) ? csr_src[base + lane] : N;   // pad -> zero row
            int steps = (nloc + 15) >> 4;       // 16 edges / iter, 2 loads in flight
            for (int j = 0; j < steps; ++j) {
                int b0 = (j << 4) | g8;
                int s0 = __shfl(sidx, b0);
                int s1 = __shfl(sidx, b0 | 8);
                uint4 u0 = *(const uint4*)(Hb + (((unsigned)s0 << 7) | qo));
                uint4 u1 = *(const uint4*)(Hb + (((unsigned)s1 << 7) | qo));
                a[0] += bflo(u0.x); a[1] += bfhi(u0.x); a[2] += bflo(u0.y); a[3] += bfhi(u0.y);
                a[4] += bflo(u0.z); a[5] += bfhi(u0.z); a[6] += bflo(u0.w); a[7] += bfhi(u0.w);
                a[0] += bflo(u1.x); a[1] += bfhi(u1.x); a[2] += bflo(u1.y); a[3] += bfhi(u1.y);
                a[4] += bflo(u1.z); a[5] += bfhi(u1.z); a[6] += bflo(u1.w); a[7] += bfhi(u1.w);
            }
        }
        rp0 = rp1;
        // LDS transpose: partials (8 groups x 64 feats) -> y[feat=lane]
        float* row = &sy[w][g8][(lane & 7) << 3];
        *(float4*)row = make_float4(a[0], a[1], a[2], a[3]);
        *(float4*)(row + 4) = make_float4(a[4], a[5], a[6], a[7]);
        __builtin_amdgcn_s_waitcnt(0);          // lgkmcnt(0): within-wave LDS order
        float ysum = sy[w][0][lane] + sy[w][1][lane] + sy[w][2][lane] + sy[w][3][lane]
                   + sy[w][4][lane] + sy[w][5][lane] + sy[w][6][lane] + sy[w][7][lane];
        float y = fmaxf(fmaf(dv, ysum, b1v), 0.f);
        // h2[c] = sum_k y[k]*W2[k][c]; group g16 covers k = g16*16..+15
        float o = 0.f;
#pragma unroll
        for (int j = 0; j < 16; ++j) o = fmaf(__shfl(y, (lane & 48) | j), w2[j], o);
        o += __shfl_xor(o, 16);
        o += __shfl_xor(o, 32);
        o *= dv;
        float oup = __shfl_xor(o, 1);
        if (lane < 16 && !(lane & 1)) {
            __hip_bfloat162 p;
            p.x = __float2bfloat16(o);
            p.y = __float2bfloat16(oup);
            *(__hip_bfloat162*)(h2s + (size_t)d * 16 + lane) = p;
        }
    }
}

// out[d] = dinv[d]*(h2s[d] + sum_in h2s[s]) + b2.  16 edges per step (uint2,
// 4 lanes/edge), dummy-row padding, float4 stores.
__global__ void k_gather2(const int* __restrict__ row_ptr, const int* __restrict__ csr_src,
                          const float* __restrict__ dinv, const __hip_bfloat16* __restrict__ h2s,
                          const float* __restrict__ b2, float* __restrict__ out) {
    int t = threadIdx.x;
    int lane = t & 63;
    int g4 = lane >> 2;                         // edge slot within step
    int q2 = lane & 3;                          // 8B feat slice
    int qo = q2 << 3;
    int wid = blockIdx.x * 4 + (t >> 6);
    int d0 = wid * NPW;
    if (d0 >= N) return;
    int dend = min(d0 + NPW, N);
    float b2v[4];
#pragma unroll
    for (int k = 0; k < 4; ++k) b2v[k] = b2[q2 * 4 + k];
    const char* Hb = (const char*)h2s;

    int rp0 = row_ptr[d0];
    for (int d = d0; d < dend; ++d) {
        int rp1 = row_ptr[d + 1];
        float dv = dinv[d];
        float a[4] = {0, 0, 0, 0};
        if (g4 == 0) {                          // self term
            uint2 u = *(const uint2*)(Hb + (((unsigned)d << 5) | qo));
            a[0] = bflo(u.x); a[1] = bfhi(u.x); a[2] = bflo(u.y); a[3] = bfhi(u.y);
        }
        for (int base = rp0; base < rp1; base += 64) {
            int nloc = min(64, rp1 - base);
            int sidx = (lane < nloc) ? csr_src[base + lane] : N;
            int steps = (nloc + 15) >> 4;
            for (int j = 0; j < steps; ++j) {
                int s = __shfl(sidx, (j << 4) | g4);
                uint2 u = *(const uint2*)(Hb + (((unsigned)s << 5) | qo));
                a[0] += bflo(u.x); a[1] += bfhi(u.x);
                a[2] += bflo(u.y); a[3] += bfhi(u.y);
            }
        }
        rp0 = rp1;
#pragma unroll
        for (int k = 0; k < 4; ++k) {
            a[k] += __shfl_xor(a[k], 4);
            a[k] += __shfl_xor(a[k], 8);
            a[k] += __shfl_xor(a[k], 16);
            a[k] += __shfl_xor(a[k], 32);
        }
        if (lane < 4) {
            float4 r;
            r.x = fmaf(dv, a[0], b2v[0]);
            r.y = fmaf(dv, a[1], b2v[1]);
            r.z = fmaf(dv, a[2], b2v[2]);
            r.w = fmaf(dv, a[3], b2v[3]);
            *(float4*)(out + (size_t)d * 16 + q2 * 4) = r;
        }
    }
}

extern "C" void kernel_launch(void* const* d_in, const int* in_sizes, int n_in,
                              void* d_out, int out_size, void* d_ws, size_t ws_size,
                              hipStream_t stream) {
    const float* X  = (const float*)d_in[0];
    const int*   ei = (const int*)d_in[1];  // [2, E] int32: src then dst
    const float* W1 = (const float*)d_in[2];
    const float* b1 = (const float*)d_in[3];
    const float* W2 = (const float*)d_in[4];
    const float* b2 = (const float*)d_in[5];
    float* out = (float*)d_out;

    int* cursor  = (int*)d_ws;                     // NB*CSTRIDE = 6272
    int* row_ptr = cursor + NB * CSTRIDE;          // N+4 (pad keeps h1s 16B-aligned)
    int* bkt     = row_ptr + N + 4;                // NB*CAP
    int* csr_src = bkt + NB * CAP;                 // E
    float* dinv  = (float*)(csr_src + E);          // N
    __hip_bfloat16* h1s = (__hip_bfloat16*)(dinv + N);  // (N+1)*64, 16B-aligned
    __hip_bfloat16* h2s = h1s + (size_t)(N + 1) * 64;   // (N+1)*16, 16B-aligned

    const int* src = ei;
    const int* dst = ei + E;

    hipMemsetAsync(cursor, 0, NB * CSTRIDE * sizeof(int), stream);
    k_bfill<<<NBLK, 256, 0, stream>>>(src, dst, cursor, bkt);
    k_bfine<<<NB, 256, 0, stream>>>(cursor, bkt, row_ptr, dinv, csr_src);
    k_gemm1<<<1024, 256, 0, stream>>>(X, W1, dinv, h1s, h2s);
    k_layer12<<<NWBLK, 256, 0, stream>>>(row_ptr, csr_src, dinv, h1s, b1, W2, h2s);
    k_gather2<<<NWBLK, 256, 0, stream>>>(row_ptr, csr_src, dinv, h2s, b2, out);
}